// Round 4
// baseline (248.125 us; speedup 1.0000x reference)
//
#include <hip/hip_runtime.h>
#include <math.h>

#define PIF 3.14159265358979323846f

// ---- all scratch as device globals (allocated at module load; no d_ws dependency) ----
__device__ float  g_norms[16];
__device__ float2 g_cs[65536];         // (cos phs, sin phs) per pixel
__device__ float  g_I[65536];          // I_est scratch copy
__device__ float2 g_SfA[256*512];      // 1 MB
__device__ float2 g_Sf [512*512];      // 2 MB
__device__ float2 g_F  [16*256*256];   // 8 MB
__device__ float2 g_KA [16*256*512];   // 16 MB
__device__ float2 g_P  [16*256*512];   // 16 MB

__device__ __forceinline__ int rev8(int x){ return (int)(__brev((unsigned)x) >> 24); }
__device__ __forceinline__ int rev9(int x){ return (int)(__brev((unsigned)x) >> 23); }

#define OUT_W(idx, val) do{ int _i = (idx); if ((unsigned)_i < (unsigned)osz) out[_i] = (val); }while(0)

// radix-2 DIF: natural input -> bit-reversed output. N/2 threads. sign=-1 fwd, +1 inv.
template<int N>
__device__ inline void fft_dif(float2* buf, int tid, float sign){
  for (int half = N >> 1; half >= 1; half >>= 1){
    __syncthreads();
    int k  = tid & (half - 1);
    int i0 = ((tid - k) << 1) + k;
    float2 a = buf[i0], b = buf[i0 + half];
    float ang = sign * PIF * (float)k / (float)half;
    float s, c; sincosf(ang, &s, &c);
    float2 d = make_float2(a.x - b.x, a.y - b.y);
    buf[i0]        = make_float2(a.x + b.x, a.y + b.y);
    buf[i0 + half] = make_float2(d.x * c - d.y * s, d.x * s + d.y * c);
  }
  __syncthreads();
}

// radix-2 DIT: bit-reversed input -> natural output. N/2 threads.
template<int N>
__device__ inline void fft_dit(float2* buf, int tid, float sign){
  for (int half = 1; half < N; half <<= 1){
    __syncthreads();
    int k  = tid & (half - 1);
    int i0 = ((tid - k) << 1) + k;
    float2 a = buf[i0], b = buf[i0 + half];
    float ang = sign * PIF * (float)k / (float)half;
    float s, c; sincosf(ang, &s, &c);
    float2 bw = make_float2(b.x * c - b.y * s, b.x * s + b.y * c);
    buf[i0]        = make_float2(a.x + bw.x, a.y + bw.y);
    buf[i0 + half] = make_float2(a.x - bw.x, a.y - bw.y);
  }
  __syncthreads();
}

// ---------------- g-MLP: one pass over 256x256 pixels (batch-independent) ----------------
__global__ __launch_bounds__(256) void k_gmlp(
    const float* gw0, const float* gb0, const float* gw1, const float* gb1,
    const float* l1w_g, const float* l1b_g, const float* gw2, const float* gb2,
    const float* l2w_g, const float* l2b_g, const float* gw3, const float* gb3,
    float* out, int osz, int offG, int offPhs, int interleaved)
{
  __shared__ float w0[60*32];
  __shared__ float w1[32*32];
  __shared__ float w2[32*32];
  __shared__ float b0[32], b1[32], b2[32], l1w[32], l1b[32], l2w[32], l2b[32], w3[32];
  __shared__ float b3s;
  int tid = threadIdx.x;
  for (int i = tid; i < 60*32; i += 256) w0[i] = gw0[i];
  for (int i = tid; i < 1024; i += 256){ w1[i] = gw1[i]; w2[i] = gw2[i]; }
  if (tid < 32){
    b0[tid]=gb0[tid]; b1[tid]=gb1[tid]; b2[tid]=gb2[tid];
    l1w[tid]=l1w_g[tid]; l1b[tid]=l1b_g[tid]; l2w[tid]=l2w_g[tid]; l2b[tid]=l2b_g[tid];
    w3[tid]=gw3[tid];
  }
  if (tid == 0) b3s = gb3[0];
  __syncthreads();

  int p = blockIdx.x * 256 + tid;
  int r = p >> 8, c = p & 255;
  float x = (float)(-1.0 + (2.0 * c) / 255.0);
  float y = (float)(-1.0 + (2.0 * r) / 255.0);

  float h0[32];
  #pragma unroll
  for (int j = 0; j < 32; j++) h0[j] = b0[j];
  for (int i = 1; i <= 15; i++){
    float sx, cx, sy, cy;
    sincosf((float)i * x, &sx, &cx);
    sincosf((float)i * y, &sy, &cy);
    const float* r0 = &w0[(4*(i-1)+0)*32];
    const float* r1 = &w0[(4*(i-1)+1)*32];
    const float* r2 = &w0[(4*(i-1)+2)*32];
    const float* r3 = &w0[(4*(i-1)+3)*32];
    #pragma unroll
    for (int j = 0; j < 32; j++)
      h0[j] += sx*r0[j] + sy*r1[j] + cx*r2[j] + cy*r3[j];
  }

  float h1[32];
  #pragma unroll
  for (int j = 0; j < 32; j++) h1[j] = b1[j];
  for (int k = 0; k < 32; k++){
    float v = h0[k];
    const float* row = &w1[k*32];
    #pragma unroll
    for (int j = 0; j < 32; j++) h1[j] += v * row[j];
  }
  {
    float m = 0.f;
    #pragma unroll
    for (int j = 0; j < 32; j++) m += h1[j];
    m *= (1.0f/32.0f);
    float vv = 0.f;
    #pragma unroll
    for (int j = 0; j < 32; j++){ float d = h1[j]-m; vv += d*d; }
    vv *= (1.0f/32.0f);
    float inv = rsqrtf(vv + 1e-5f);
    #pragma unroll
    for (int j = 0; j < 32; j++){
      float t = (h1[j]-m)*inv*l1w[j] + l1b[j];
      h1[j] = (t > 0.f) ? t : 0.01f*t;
    }
  }

  float h2[32];
  #pragma unroll
  for (int j = 0; j < 32; j++) h2[j] = b2[j];
  for (int k = 0; k < 32; k++){
    float v = h1[k];
    const float* row = &w2[k*32];
    #pragma unroll
    for (int j = 0; j < 32; j++) h2[j] += v * row[j];
  }
  {
    float m = 0.f;
    #pragma unroll
    for (int j = 0; j < 32; j++) m += h2[j];
    m *= (1.0f/32.0f);
    float vv = 0.f;
    #pragma unroll
    for (int j = 0; j < 32; j++){ float d = h2[j]-m; vv += d*d; }
    vv *= (1.0f/32.0f);
    float inv = rsqrtf(vv + 1e-5f);
    #pragma unroll
    for (int j = 0; j < 32; j++){
      float t = (h2[j]-m)*inv*l2w[j] + l2b[j];
      h2[j] = (t > 0.f) ? t : 0.01f*t;
    }
  }

  float phs = b3s;
  #pragma unroll
  for (int k = 0; k < 32; k++) phs += h2[k]*w3[k];

  float sp, cp; sincosf(phs, &sp, &cp);
  g_cs[p] = make_float2(cp, sp);

  #pragma unroll
  for (int b = 0; b < 16; b++){
    OUT_W(offPhs + b*65536 + p, phs);
    if (interleaved){
      OUT_W(offG + 2*(b*65536 + p),     cp);
      OUT_W(offG + 2*(b*65536 + p) + 1, sp);
    } else {
      OUT_W(offG + b*65536 + p, cp);
    }
  }
}

// ---------------- patch MLPs -> I_est ----------------
__global__ __launch_bounds__(256) void k_patch(
    const float* pdata, const float* rw0, const float* rb0,
    const float* rw1, const float* rb1, const float* rw2, const float* rb2,
    float* out, int osz, int offIest)
{
  __shared__ float w0[1024];
  __shared__ float w1[1024];
  __shared__ float b0[32], b1[32], w2[32];
  __shared__ float b2s;
  int patch = blockIdx.x >> 6;
  int tid = threadIdx.x;
  for (int i = tid; i < 1024; i += 256){ w0[i] = rw0[patch*1024 + i]; w1[i] = rw1[patch*1024 + i]; }
  if (tid < 32){ b0[tid]=rb0[patch*32+tid]; b1[tid]=rb1[patch*32+tid]; w2[tid]=rw2[patch*32+tid]; }
  if (tid == 0) b2s = rb2[patch];
  __syncthreads();

  int p = (blockIdx.x & 63) * 256 + tid;
  int i = p >> 7, j = p & 127;
  int i1 = min(i+1, 127), j1 = min(j+1, 127);
  const float* base = pdata + (size_t)patch * 128*128*32;
  const float* d00 = base + (i*128 + j )*32;
  const float* d01 = base + (i*128 + j1)*32;
  const float* d10 = base + (i1*128 + j )*32;
  const float* d11 = base + (i1*128 + j1)*32;

  float f[32];
  #pragma unroll
  for (int k = 0; k < 32; k++) f[k] = 0.25f*(d00[k]+d01[k]+d10[k]+d11[k]);

  float h[32];
  #pragma unroll
  for (int q = 0; q < 32; q++) h[q] = b0[q];
  for (int k = 0; k < 32; k++){
    float v = f[k];
    const float* row = &w0[k*32];
    #pragma unroll
    for (int q = 0; q < 32; q++) h[q] += v*row[q];
  }
  #pragma unroll
  for (int q = 0; q < 32; q++) h[q] = fmaxf(h[q], 0.f);

  float g[32];
  #pragma unroll
  for (int q = 0; q < 32; q++) g[q] = b1[q];
  for (int k = 0; k < 32; k++){
    float v = h[k];
    const float* row = &w1[k*32];
    #pragma unroll
    for (int q = 0; q < 32; q++) g[q] += v*row[q];
  }
  float o = b2s;
  #pragma unroll
  for (int k = 0; k < 32; k++) o += fmaxf(g[k], 0.f)*w2[k];

  int pr = (patch >> 1)*128 + i;
  int pc = (patch & 1)*128 + j;
  g_I[pr*256 + pc] = o;
  OUT_W(offIest + pr*256 + pc, o);
}

// ---------------- per-image norm = 65536 * sum(x^2) (Parseval) ----------------
__global__ __launch_bounds__(256) void k_norm(const float* x){
  int b = blockIdx.x, tid = threadIdx.x;
  const float* xb = x + (size_t)b*65536;
  float s = 0.f;
  for (int i = tid; i < 65536; i += 256){ float v = xb[i]; s += v*v; }
  __shared__ float red[256];
  red[tid] = s; __syncthreads();
  for (int w = 128; w > 0; w >>= 1){ if (tid < w) red[tid] += red[tid+w]; __syncthreads(); }
  if (tid == 0) g_norms[b] = 65536.0f * red[0];
}

// ---------------- field FFT (256): rows (reads cos/sin from g_cs) ----------------
__global__ __launch_bounds__(128) void k_fft_field_row(const float* x){
  int b = blockIdx.x >> 8, r = blockIdx.x & 255;
  __shared__ float2 buf[256];
  int tid = threadIdx.x;
  for (int e = tid; e < 256; e += 128){
    float xv = x[((size_t)b*256 + r)*256 + e];
    float2 cs = g_cs[r*256 + e];
    buf[e] = make_float2(xv*cs.x, xv*cs.y);
  }
  fft_dif<256>(buf, tid, -1.0f);
  for (int e = tid; e < 256; e += 128)
    g_F[((size_t)b*256 + r)*256 + rev8(e)] = buf[e];
}

// ---------------- field FFT: cols (in place) ----------------
__global__ __launch_bounds__(128) void k_fft_field_col(){
  int b = blockIdx.x >> 8, c = blockIdx.x & 255;
  __shared__ float2 buf[256];
  int tid = threadIdx.x;
  for (int e = tid; e < 256; e += 128) buf[e] = g_F[((size_t)b*256 + e)*256 + c];
  fft_dif<256>(buf, tid, -1.0f);
  for (int e = tid; e < 256; e += 128) g_F[((size_t)b*256 + rev8(e))*256 + c] = buf[e];
}

// ------- fused: kernel magnitude (shift+flip+normalize) -> d_out, then padded row FFT -> KA -------
__global__ __launch_bounds__(256) void k_mag_krow(float* out, int osz, int offKer){
  int b = blockIdx.x >> 8, r = blockIdx.x & 255;
  __shared__ float2 buf[512];
  int tid = threadIdx.x;
  float invn = 1.0f / g_norms[b];
  int a = (127 - r) & 255;
  for (int e = tid; e < 512; e += 256){
    float kv = 0.f;
    if (e < 256){
      int bb = (127 - e) & 255;
      float2 f = g_F[((size_t)b*256 + a)*256 + bb];
      kv = (f.x*f.x + f.y*f.y) * invn;
      OUT_W(offKer + b*65536 + r*256 + e, kv);
    }
    buf[e] = make_float2(kv, 0.f);
  }
  fft_dif<512>(buf, tid, -1.0f);
  for (int e = tid; e < 512; e += 256) g_KA[((size_t)b*256 + r)*512 + rev9(e)] = buf[e];
}

// ---------------- Sf = FFT2(pad512(I_est)) ----------------
__global__ __launch_bounds__(256) void k_fft_S_row(){
  int r = blockIdx.x;
  __shared__ float2 buf[512];
  int tid = threadIdx.x;
  for (int e = tid; e < 512; e += 256)
    buf[e] = make_float2(e < 256 ? g_I[r*256 + e] : 0.f, 0.f);
  fft_dif<512>(buf, tid, -1.0f);
  for (int e = tid; e < 512; e += 256) g_SfA[r*512 + rev9(e)] = buf[e];
}

__global__ __launch_bounds__(256) void k_fft_S_col(){
  int c = blockIdx.x;
  __shared__ float2 buf[512];
  int tid = threadIdx.x;
  for (int e = tid; e < 512; e += 256)
    buf[e] = (e < 256) ? g_SfA[e*512 + c] : make_float2(0.f, 0.f);
  fft_dif<512>(buf, tid, -1.0f);
  for (int e = tid; e < 512; e += 256) g_Sf[rev9(e)*512 + c] = buf[e];
}

// ------- fused: Kf col FFT -> *Sf (bit-rev aligned) -> inverse col FFT; keep rows 128..383 -------
__global__ __launch_bounds__(256) void k_col_mul_inv(){
  int b = blockIdx.x >> 9, v = blockIdx.x & 511;
  __shared__ float2 buf[512];
  int tid = threadIdx.x;
  for (int e = tid; e < 512; e += 256)
    buf[e] = (e < 256) ? g_KA[((size_t)b*256 + e)*512 + v] : make_float2(0.f, 0.f);
  fft_dif<512>(buf, tid, -1.0f);        // buf[j] = Kf[rev9(j), v]
  for (int e = tid; e < 512; e += 256){
    float2 s = g_Sf[(size_t)rev9(e)*512 + v];
    float2 k = buf[e];
    buf[e] = make_float2(k.x*s.x - k.y*s.y, k.x*s.y + k.y*s.x);
  }
  fft_dit<512>(buf, tid, +1.0f);        // bit-rev in -> natural out (inverse along u)
  for (int e = tid; e < 512; e += 256)
    if (e >= 128 && e < 384)
      g_P[((size_t)b*256 + (e - 128))*512 + v] = buf[e];
}

// ---------------- inverse row FFT + crop + scale + real ----------------
__global__ __launch_bounds__(256) void k_ifft_row(float* out, int osz){
  int b = blockIdx.x >> 8, ri = blockIdx.x & 255;
  __shared__ float2 buf[512];
  int tid = threadIdx.x;
  for (int e = tid; e < 512; e += 256) buf[e] = g_P[((size_t)b*256 + ri)*512 + e];
  fft_dif<512>(buf, tid, +1.0f);        // inverse, natural in -> bit-rev out
  const float sc = 1.0f / 262144.0f;    // 1/(512*512)
  for (int e = tid; e < 512; e += 256){
    int vo = rev9(e);
    if (vo >= 128 && vo < 384)
      OUT_W(b*65536 + ri*256 + (vo - 128), buf[e].x * sc);
  }
}

extern "C" void kernel_launch(void* const* d_in, const int* in_sizes, int n_in,
                              void* d_out, int out_size, void* d_ws, size_t ws_size,
                              hipStream_t stream) {
  // ---- verify input ordering/sizes; if unexpected, launch nothing (clean diagnostic fail) ----
  static const int expect[21] = {
    16*65536,      // x_batch
    16,            // t
    4*128*128*32,  // patch_data
    4*32*32, 4*32, // r_w0, r_b0
    4*32*32, 4*32, // r_w1, r_b1
    4*32, 4,       // r_w2, r_b2
    60*32, 32,     // g_w0, g_b0
    32*32, 32,     // g_w1, g_b1
    32, 32,        // ln1_w, ln1_b
    32*32, 32,     // g_w2, g_b2
    32, 32,        // ln2_w, ln2_b
    32, 1          // g_w3, g_b3
  };
  if (n_in < 21) return;
  for (int i = 0; i < 21; i++) if (in_sizes[i] != expect[i]) return;

  const float* x_batch = (const float*)d_in[0];
  const float* pdata = (const float*)d_in[2];
  const float* rw0 = (const float*)d_in[3];
  const float* rb0 = (const float*)d_in[4];
  const float* rw1 = (const float*)d_in[5];
  const float* rb1 = (const float*)d_in[6];
  const float* rw2 = (const float*)d_in[7];
  const float* rb2 = (const float*)d_in[8];
  const float* gw0 = (const float*)d_in[9];
  const float* gb0 = (const float*)d_in[10];
  const float* gw1 = (const float*)d_in[11];
  const float* gb1 = (const float*)d_in[12];
  const float* l1w = (const float*)d_in[13];
  const float* l1b = (const float*)d_in[14];
  const float* gw2 = (const float*)d_in[15];
  const float* gb2 = (const float*)d_in[16];
  const float* l2w = (const float*)d_in[17];
  const float* l2b = (const float*)d_in[18];
  const float* gw3 = (const float*)d_in[19];
  const float* gb3 = (const float*)d_in[20];

  float* out = (float*)d_out;

  // ---- output layout, adaptive on out_size ----
  // L1 (complex64 stored as 2 floats, interleaved): total 5,308,416
  // L2 (complex64 slot counted once, real-only):     total 4,259,840
  int interleaved = (out_size >= 5308416) ? 1 : 0;
  int offKer  = 1048576;
  int offG    = 2097152;
  int offPhs  = interleaved ? 4194304 : 3145728;
  int offIest = interleaved ? 5242880 : 4194304;

  k_gmlp<<<256, 256, 0, stream>>>(gw0, gb0, gw1, gb1, l1w, l1b, gw2, gb2,
                                  l2w, l2b, gw3, gb3, out, out_size, offG, offPhs, interleaved);
  k_patch<<<256, 256, 0, stream>>>(pdata, rw0, rb0, rw1, rb1, rw2, rb2, out, out_size, offIest);
  k_norm<<<16, 256, 0, stream>>>(x_batch);
  k_fft_S_row<<<256, 256, 0, stream>>>();
  k_fft_S_col<<<512, 256, 0, stream>>>();
  k_fft_field_row<<<4096, 128, 0, stream>>>(x_batch);
  k_fft_field_col<<<4096, 128, 0, stream>>>();
  k_mag_krow<<<4096, 256, 0, stream>>>(out, out_size, offKer);
  k_col_mul_inv<<<8192, 256, 0, stream>>>();
  k_ifft_row<<<4096, 256, 0, stream>>>(out, out_size);
}

// Round 5
// 174.437 us; speedup vs baseline: 1.4224x; 1.4224x over previous
//
#include <hip/hip_runtime.h>
#include <math.h>

// ---- all scratch as device globals (allocated at module load; no d_ws dependency) ----
__device__ float  g_norms[16];
__device__ float  g_partial[1024];
__device__ float2 g_cs[65536];         // (cos phs, sin phs) per pixel
__device__ float  g_I[65536];          // I_est scratch copy
__device__ float2 g_tw[512];           // tw[h+k] = exp(-i*pi*k/h), h=1,2,4,...,256
__device__ float2 g_SfA[256*512];      // 1 MB
__device__ float2 g_Sf [512*512];      // 2 MB
__device__ float2 g_F  [16*256*256];   // 8 MB
__device__ float2 g_KA [16*256*512];   // 16 MB
__device__ float2 g_P  [16*256*512];   // 16 MB

__device__ __forceinline__ int rev8(int x){ return (int)(__brev((unsigned)x) >> 24); }
__device__ __forceinline__ int rev9(int x){ return (int)(__brev((unsigned)x) >> 23); }

#define OUT_W(idx, val) do{ int _i = (idx); if ((unsigned)_i < (unsigned)osz) out[_i] = (val); }while(0)

// ---- twiddle table init (once per call; ~1us) ----
__global__ void k_twiddle(){
  int i = blockIdx.x*256 + threadIdx.x;
  if (i >= 512) return;
  if (i == 0){ g_tw[0] = make_float2(1.f, 0.f); return; }
  int h = 1 << (31 - __clz(i));
  int k = i - h;
  double a = -M_PI * (double)k / (double)h;
  g_tw[i] = make_float2((float)cos(a), (float)sin(a));
}

// ---- single-column FFTs, separate re/im (stride-1 float -> conflict-free) ----
// DIF: natural in -> bit-reversed out.
template<int N, bool INV>
__device__ inline void fft_dif_sc(float* re, float* im, int tid, int nthr){
  for (int half = N >> 1; half >= 1; half >>= 1){
    __syncthreads();
    for (int b = tid; b < (N>>1); b += nthr){
      int k  = b & (half - 1);
      int i0 = ((b - k) << 1) + k;
      int i1 = i0 + half;
      float2 w = g_tw[half + k];
      float wy = INV ? -w.y : w.y;
      float ar = re[i0], ai = im[i0], br = re[i1], bi = im[i1];
      float dr = ar - br, di = ai - bi;
      re[i0] = ar + br; im[i0] = ai + bi;
      re[i1] = dr*w.x - di*wy;
      im[i1] = dr*wy + di*w.x;
    }
  }
  __syncthreads();
}

// ---- multi-column (8 cols/block) FFTs, LDS layout [N][9] floats, separate re/im ----
template<int N, bool INV>
__device__ inline void fft_dif_mc(float* re, float* im, int tid){
  int c = tid & 7, rr = tid >> 3;
  for (int half = N >> 1; half >= 1; half >>= 1){
    __syncthreads();
    for (int b = rr; b < (N>>1); b += 32){
      int k  = b & (half - 1);
      int r0 = ((b - k) << 1) + k;
      int i0 = r0*9 + c, i1 = (r0+half)*9 + c;
      float2 w = g_tw[half + k];
      float wy = INV ? -w.y : w.y;
      float ar = re[i0], ai = im[i0], br = re[i1], bi = im[i1];
      float dr = ar - br, di = ai - bi;
      re[i0] = ar + br; im[i0] = ai + bi;
      re[i1] = dr*w.x - di*wy;
      im[i1] = dr*wy + di*w.x;
    }
  }
  __syncthreads();
}

// DIT: bit-reversed in -> natural out.
template<int N, bool INV>
__device__ inline void fft_dit_mc(float* re, float* im, int tid){
  int c = tid & 7, rr = tid >> 3;
  for (int half = 1; half < N; half <<= 1){
    __syncthreads();
    for (int b = rr; b < (N>>1); b += 32){
      int k  = b & (half - 1);
      int r0 = ((b - k) << 1) + k;
      int i0 = r0*9 + c, i1 = (r0+half)*9 + c;
      float2 w = g_tw[half + k];
      float wy = INV ? -w.y : w.y;
      float br = re[i1], bi = im[i1];
      float tr = br*w.x - bi*wy, ti = br*wy + bi*w.x;
      float ar = re[i0], ai = im[i0];
      re[i0] = ar + tr; im[i0] = ai + ti;
      re[i1] = ar - tr; im[i1] = ai - ti;
    }
  }
  __syncthreads();
}

// ---------------- g-MLP: one pass over 256x256 pixels (batch-independent) ----------------
__global__ __launch_bounds__(256) void k_gmlp(
    const float* gw0, const float* gb0, const float* gw1, const float* gb1,
    const float* l1w_g, const float* l1b_g, const float* gw2, const float* gb2,
    const float* l2w_g, const float* l2b_g, const float* gw3, const float* gb3,
    float* out, int osz, int offG, int offPhs, int interleaved)
{
  __shared__ float w0[60*32];
  __shared__ float w1[32*32];
  __shared__ float w2[32*32];
  __shared__ float b0[32], b1[32], b2[32], l1w[32], l1b[32], l2w[32], l2b[32], w3[32];
  __shared__ float b3s;
  int tid = threadIdx.x;
  for (int i = tid; i < 60*32; i += 256) w0[i] = gw0[i];
  for (int i = tid; i < 1024; i += 256){ w1[i] = gw1[i]; w2[i] = gw2[i]; }
  if (tid < 32){
    b0[tid]=gb0[tid]; b1[tid]=gb1[tid]; b2[tid]=gb2[tid];
    l1w[tid]=l1w_g[tid]; l1b[tid]=l1b_g[tid]; l2w[tid]=l2w_g[tid]; l2b[tid]=l2b_g[tid];
    w3[tid]=gw3[tid];
  }
  if (tid == 0) b3s = gb3[0];
  __syncthreads();

  int p = blockIdx.x * 256 + tid;
  int r = p >> 8, c = p & 255;
  float x = (float)(-1.0 + (2.0 * c) / 255.0);
  float y = (float)(-1.0 + (2.0 * r) / 255.0);

  float h0[32];
  #pragma unroll
  for (int j = 0; j < 32; j++) h0[j] = b0[j];
  for (int i = 1; i <= 15; i++){
    float sx, cx, sy, cy;
    sincosf((float)i * x, &sx, &cx);
    sincosf((float)i * y, &sy, &cy);
    const float* r0 = &w0[(4*(i-1)+0)*32];
    const float* r1 = &w0[(4*(i-1)+1)*32];
    const float* r2 = &w0[(4*(i-1)+2)*32];
    const float* r3 = &w0[(4*(i-1)+3)*32];
    #pragma unroll
    for (int j = 0; j < 32; j++)
      h0[j] += sx*r0[j] + sy*r1[j] + cx*r2[j] + cy*r3[j];
  }

  float h1[32];
  #pragma unroll
  for (int j = 0; j < 32; j++) h1[j] = b1[j];
  for (int k = 0; k < 32; k++){
    float v = h0[k];
    const float* row = &w1[k*32];
    #pragma unroll
    for (int j = 0; j < 32; j++) h1[j] += v * row[j];
  }
  {
    float m = 0.f;
    #pragma unroll
    for (int j = 0; j < 32; j++) m += h1[j];
    m *= (1.0f/32.0f);
    float vv = 0.f;
    #pragma unroll
    for (int j = 0; j < 32; j++){ float d = h1[j]-m; vv += d*d; }
    vv *= (1.0f/32.0f);
    float inv = rsqrtf(vv + 1e-5f);
    #pragma unroll
    for (int j = 0; j < 32; j++){
      float t = (h1[j]-m)*inv*l1w[j] + l1b[j];
      h1[j] = (t > 0.f) ? t : 0.01f*t;
    }
  }

  float h2[32];
  #pragma unroll
  for (int j = 0; j < 32; j++) h2[j] = b2[j];
  for (int k = 0; k < 32; k++){
    float v = h1[k];
    const float* row = &w2[k*32];
    #pragma unroll
    for (int j = 0; j < 32; j++) h2[j] += v * row[j];
  }
  {
    float m = 0.f;
    #pragma unroll
    for (int j = 0; j < 32; j++) m += h2[j];
    m *= (1.0f/32.0f);
    float vv = 0.f;
    #pragma unroll
    for (int j = 0; j < 32; j++){ float d = h2[j]-m; vv += d*d; }
    vv *= (1.0f/32.0f);
    float inv = rsqrtf(vv + 1e-5f);
    #pragma unroll
    for (int j = 0; j < 32; j++){
      float t = (h2[j]-m)*inv*l2w[j] + l2b[j];
      h2[j] = (t > 0.f) ? t : 0.01f*t;
    }
  }

  float phs = b3s;
  #pragma unroll
  for (int k = 0; k < 32; k++) phs += h2[k]*w3[k];

  float sp, cp; sincosf(phs, &sp, &cp);
  g_cs[p] = make_float2(cp, sp);

  #pragma unroll
  for (int b = 0; b < 16; b++){
    OUT_W(offPhs + b*65536 + p, phs);
    if (interleaved){
      OUT_W(offG + 2*(b*65536 + p),     cp);
      OUT_W(offG + 2*(b*65536 + p) + 1, sp);
    } else {
      OUT_W(offG + b*65536 + p, cp);
    }
  }
}

// ---------------- patch MLPs -> I_est ----------------
__global__ __launch_bounds__(256) void k_patch(
    const float* pdata, const float* rw0, const float* rb0,
    const float* rw1, const float* rb1, const float* rw2, const float* rb2,
    float* out, int osz, int offIest)
{
  __shared__ float w0[1024];
  __shared__ float w1[1024];
  __shared__ float b0[32], b1[32], w2[32];
  __shared__ float b2s;
  int patch = blockIdx.x >> 6;
  int tid = threadIdx.x;
  for (int i = tid; i < 1024; i += 256){ w0[i] = rw0[patch*1024 + i]; w1[i] = rw1[patch*1024 + i]; }
  if (tid < 32){ b0[tid]=rb0[patch*32+tid]; b1[tid]=rb1[patch*32+tid]; w2[tid]=rw2[patch*32+tid]; }
  if (tid == 0) b2s = rb2[patch];
  __syncthreads();

  int p = (blockIdx.x & 63) * 256 + tid;
  int i = p >> 7, j = p & 127;
  int i1 = min(i+1, 127), j1 = min(j+1, 127);
  const float* base = pdata + (size_t)patch * 128*128*32;
  const float* d00 = base + (i*128 + j )*32;
  const float* d01 = base + (i*128 + j1)*32;
  const float* d10 = base + (i1*128 + j )*32;
  const float* d11 = base + (i1*128 + j1)*32;

  float f[32];
  #pragma unroll
  for (int k = 0; k < 32; k++) f[k] = 0.25f*(d00[k]+d01[k]+d10[k]+d11[k]);

  float h[32];
  #pragma unroll
  for (int q = 0; q < 32; q++) h[q] = b0[q];
  for (int k = 0; k < 32; k++){
    float v = f[k];
    const float* row = &w0[k*32];
    #pragma unroll
    for (int q = 0; q < 32; q++) h[q] += v*row[q];
  }
  #pragma unroll
  for (int q = 0; q < 32; q++) h[q] = fmaxf(h[q], 0.f);

  float g[32];
  #pragma unroll
  for (int q = 0; q < 32; q++) g[q] = b1[q];
  for (int k = 0; k < 32; k++){
    float v = h[k];
    const float* row = &w1[k*32];
    #pragma unroll
    for (int q = 0; q < 32; q++) g[q] += v*row[q];
  }
  float o = b2s;
  #pragma unroll
  for (int k = 0; k < 32; k++) o += fmaxf(g[k], 0.f)*w2[k];

  int pr = (patch >> 1)*128 + i;
  int pc = (patch & 1)*128 + j;
  g_I[pr*256 + pc] = o;
  OUT_W(offIest + pr*256 + pc, o);
}

// ---------------- norm = 65536*sum(x^2), two-stage ----------------
__global__ __launch_bounds__(256) void k_norm1(const float* x){
  int tid = threadIdx.x;
  float4 v = ((const float4*)x)[(size_t)blockIdx.x*256 + tid];
  float s = v.x*v.x + v.y*v.y + v.z*v.z + v.w*v.w;
  __shared__ float red[256];
  red[tid] = s; __syncthreads();
  for (int w = 128; w > 0; w >>= 1){ if (tid < w) red[tid] += red[tid+w]; __syncthreads(); }
  if (tid == 0) g_partial[blockIdx.x] = red[0];
}

__global__ __launch_bounds__(256) void k_norm2(){
  int tid = threadIdx.x;
  int b = tid >> 4, l = tid & 15;
  float s = 0.f;
  #pragma unroll
  for (int j = 0; j < 4; j++) s += g_partial[b*64 + l + 16*j];
  #pragma unroll
  for (int d = 8; d > 0; d >>= 1) s += __shfl_down(s, d, 16);
  if (l == 0) g_norms[b] = 65536.0f * s;
}

// ---------------- field FFT (256): rows ----------------
__global__ __launch_bounds__(128) void k_fft_field_row(const float* x){
  int b = blockIdx.x >> 8, r = blockIdx.x & 255;
  __shared__ float re[256], im[256];
  int tid = threadIdx.x;
  for (int e = tid; e < 256; e += 128){
    float xv = x[((size_t)b*256 + r)*256 + e];
    float2 cs = g_cs[r*256 + e];
    re[e] = xv*cs.x; im[e] = xv*cs.y;
  }
  fft_dif_sc<256,false>(re, im, tid, 128);
  for (int e = tid; e < 256; e += 128)
    g_F[((size_t)b*256 + r)*256 + rev8(e)] = make_float2(re[e], im[e]);
}

// ---------------- field FFT: cols, 8 per block, in place ----------------
__global__ __launch_bounds__(256) void k_fft_field_col(){
  __shared__ float re[256*9], im[256*9];
  int b = blockIdx.x >> 5, v0 = (blockIdx.x & 31) << 3;
  int tid = threadIdx.x, c = tid & 7, rr = tid >> 3;
  for (int r = rr; r < 256; r += 32){
    float2 f = g_F[((size_t)b*256 + r)*256 + v0 + c];
    re[r*9+c] = f.x; im[r*9+c] = f.y;
  }
  fft_dif_mc<256,false>(re, im, tid);
  for (int r = rr; r < 256; r += 32)
    g_F[((size_t)b*256 + rev8(r))*256 + v0 + c] = make_float2(re[r*9+c], im[r*9+c]);
}

// ------- fused: kernel magnitude (shift+flip+normalize) -> d_out, then padded row FFT -> KA -------
__global__ __launch_bounds__(256) void k_mag_krow(float* out, int osz, int offKer){
  int b = blockIdx.x >> 8, r = blockIdx.x & 255;
  __shared__ float re[512], im[512];
  int tid = threadIdx.x;
  float invn = 1.0f / g_norms[b];
  int a = (127 - r) & 255;
  for (int e = tid; e < 512; e += 256){
    float kv = 0.f;
    if (e < 256){
      int bb = (127 - e) & 255;
      float2 f = g_F[((size_t)b*256 + a)*256 + bb];
      kv = (f.x*f.x + f.y*f.y) * invn;
      OUT_W(offKer + b*65536 + r*256 + e, kv);
    }
    re[e] = kv; im[e] = 0.f;
  }
  fft_dif_sc<512,false>(re, im, tid, 256);
  for (int e = tid; e < 512; e += 256)
    g_KA[((size_t)b*256 + r)*512 + rev9(e)] = make_float2(re[e], im[e]);
}

// ---------------- Sf = FFT2(pad512(I_est)) ----------------
__global__ __launch_bounds__(256) void k_fft_S_row(){
  int r = blockIdx.x;
  __shared__ float re[512], im[512];
  int tid = threadIdx.x;
  for (int e = tid; e < 512; e += 256){
    re[e] = (e < 256) ? g_I[r*256 + e] : 0.f;
    im[e] = 0.f;
  }
  fft_dif_sc<512,false>(re, im, tid, 256);
  for (int e = tid; e < 512; e += 256) g_SfA[r*512 + rev9(e)] = make_float2(re[e], im[e]);
}

__global__ __launch_bounds__(256) void k_fft_S_col(){
  int cidx = blockIdx.x;
  __shared__ float re[512], im[512];
  int tid = threadIdx.x;
  for (int e = tid; e < 512; e += 256){
    if (e < 256){ float2 f = g_SfA[e*512 + cidx]; re[e] = f.x; im[e] = f.y; }
    else { re[e] = 0.f; im[e] = 0.f; }
  }
  fft_dif_sc<512,false>(re, im, tid, 256);
  for (int e = tid; e < 512; e += 256) g_Sf[rev9(e)*512 + cidx] = make_float2(re[e], im[e]);
}

// ------- fused: Kf col FFT -> *Sf (bit-rev aligned) -> inverse col FFT; 8 cols/block -------
__global__ __launch_bounds__(256) void k_col_mul_inv(){
  __shared__ float re[512*9], im[512*9];
  int b = blockIdx.x >> 6, v0 = (blockIdx.x & 63) << 3;
  int tid = threadIdx.x, c = tid & 7, rr = tid >> 3;
  for (int r = rr; r < 256; r += 32){
    float2 kv = g_KA[((size_t)b*256 + r)*512 + v0 + c];
    re[r*9+c] = kv.x; im[r*9+c] = kv.y;
  }
  for (int r = 256 + rr; r < 512; r += 32){ re[r*9+c] = 0.f; im[r*9+c] = 0.f; }
  fft_dif_mc<512,false>(re, im, tid);          // -> Kf[rev9(e), v]
  for (int e = rr; e < 512; e += 32){
    float2 s = g_Sf[(size_t)rev9(e)*512 + v0 + c];
    int idx = e*9 + c;
    float kr = re[idx], ki = im[idx];
    re[idx] = kr*s.x - ki*s.y;
    im[idx] = kr*s.y + ki*s.x;
  }
  fft_dit_mc<512,true>(re, im, tid);           // bit-rev in -> natural out (inverse along u)
  for (int r = 128 + rr; r < 384; r += 32)
    g_P[((size_t)b*256 + (r-128))*512 + v0 + c] = make_float2(re[r*9+c], im[r*9+c]);
}

// ---------------- inverse row FFT + crop + scale + real ----------------
__global__ __launch_bounds__(256) void k_ifft_row(float* out, int osz){
  int b = blockIdx.x >> 8, ri = blockIdx.x & 255;
  __shared__ float re[512], im[512];
  int tid = threadIdx.x;
  for (int e = tid; e < 512; e += 256){
    float2 p = g_P[((size_t)b*256 + ri)*512 + e];
    re[e] = p.x; im[e] = p.y;
  }
  fft_dif_sc<512,true>(re, im, tid, 256);      // inverse, natural in -> bit-rev out
  const float sc = 1.0f / 262144.0f;           // 1/(512*512)
  for (int e = tid; e < 512; e += 256){
    int vo = rev9(e);
    if (vo >= 128 && vo < 384)
      OUT_W(b*65536 + ri*256 + (vo - 128), re[e] * sc);
  }
}

extern "C" void kernel_launch(void* const* d_in, const int* in_sizes, int n_in,
                              void* d_out, int out_size, void* d_ws, size_t ws_size,
                              hipStream_t stream) {
  // ---- verify input ordering/sizes; if unexpected, launch nothing (clean diagnostic fail) ----
  static const int expect[21] = {
    16*65536, 16, 4*128*128*32,
    4*32*32, 4*32, 4*32*32, 4*32, 4*32, 4,
    60*32, 32, 32*32, 32, 32, 32, 32*32, 32, 32, 32, 32, 1
  };
  if (n_in < 21) return;
  for (int i = 0; i < 21; i++) if (in_sizes[i] != expect[i]) return;

  const float* x_batch = (const float*)d_in[0];
  const float* pdata = (const float*)d_in[2];
  const float* rw0 = (const float*)d_in[3];
  const float* rb0 = (const float*)d_in[4];
  const float* rw1 = (const float*)d_in[5];
  const float* rb1 = (const float*)d_in[6];
  const float* rw2 = (const float*)d_in[7];
  const float* rb2 = (const float*)d_in[8];
  const float* gw0 = (const float*)d_in[9];
  const float* gb0 = (const float*)d_in[10];
  const float* gw1 = (const float*)d_in[11];
  const float* gb1 = (const float*)d_in[12];
  const float* l1w = (const float*)d_in[13];
  const float* l1b = (const float*)d_in[14];
  const float* gw2 = (const float*)d_in[15];
  const float* gb2 = (const float*)d_in[16];
  const float* l2w = (const float*)d_in[17];
  const float* l2b = (const float*)d_in[18];
  const float* gw3 = (const float*)d_in[19];
  const float* gb3 = (const float*)d_in[20];

  float* out = (float*)d_out;

  // ---- output layout, adaptive on out_size ----
  int interleaved = (out_size >= 5308416) ? 1 : 0;
  int offKer  = 1048576;
  int offG    = 2097152;
  int offPhs  = interleaved ? 4194304 : 3145728;
  int offIest = interleaved ? 5242880 : 4194304;

  k_twiddle<<<2, 256, 0, stream>>>();
  k_gmlp<<<256, 256, 0, stream>>>(gw0, gb0, gw1, gb1, l1w, l1b, gw2, gb2,
                                  l2w, l2b, gw3, gb3, out, out_size, offG, offPhs, interleaved);
  k_patch<<<256, 256, 0, stream>>>(pdata, rw0, rb0, rw1, rb1, rw2, rb2, out, out_size, offIest);
  k_norm1<<<1024, 256, 0, stream>>>(x_batch);
  k_norm2<<<1, 256, 0, stream>>>();
  k_fft_S_row<<<256, 256, 0, stream>>>();
  k_fft_S_col<<<512, 256, 0, stream>>>();
  k_fft_field_row<<<4096, 128, 0, stream>>>(x_batch);
  k_fft_field_col<<<512, 256, 0, stream>>>();
  k_mag_krow<<<4096, 256, 0, stream>>>(out, out_size, offKer);
  k_col_mul_inv<<<1024, 256, 0, stream>>>();
  k_ifft_row<<<4096, 256, 0, stream>>>(out, out_size);
}

// Round 6
// 146.465 us; speedup vs baseline: 1.6941x; 1.1910x over previous
//
#include <hip/hip_runtime.h>
#include <math.h>

// ---- all scratch as device globals (allocated at module load; no d_ws dependency) ----
__device__ float  g_norms[16];
__device__ float  g_partial[1024];
__device__ float2 g_cs[65536];         // (cos phs, sin phs) per pixel
__device__ float  g_I[65536];          // I_est scratch copy
__device__ float2 g_tw[512];           // tw[h+k] = exp(-i*pi*k/h), h=1,2,4,...,256
__device__ float2 g_SfA[256*512];      // 1 MB
__device__ float2 g_Sf [512*512];      // 2 MB (stored in mixed-radix pi order)
__device__ float2 g_F  [16*256*256];   // 8 MB
__device__ float2 g_KA [16*256*512];   // 16 MB
__device__ float2 g_P  [16*256*512];   // 16 MB

__device__ __forceinline__ int rev8(int x){ return (int)(__brev((unsigned)x) >> 24); }
__device__ __forceinline__ int rev9(int x){ return (int)(__brev((unsigned)x) >> 23); }
// base-4 digit reversal of an 8-bit index (involution)
__device__ __forceinline__ int rev4d8(int x){
  return ((x&3)<<6) | (((x>>2)&3)<<4) | (((x>>4)&3)<<2) | ((x>>6)&3);
}

__device__ __forceinline__ float2 cadd(float2 a, float2 b){ return make_float2(a.x+b.x, a.y+b.y); }
__device__ __forceinline__ float2 csub(float2 a, float2 b){ return make_float2(a.x-b.x, a.y-b.y); }
__device__ __forceinline__ float2 cmul(float2 a, float2 b){ return make_float2(a.x*b.x - a.y*b.y, a.x*b.y + a.y*b.x); }
__device__ __forceinline__ float2 cmulj(float2 a, float2 b){ return make_float2(a.x*b.x + a.y*b.y, a.y*b.x - a.x*b.y); } // a*conj(b)
__device__ __forceinline__ float2 addi(float2 a, float2 b){ return make_float2(a.x - b.y, a.y + b.x); } // a + i*b
__device__ __forceinline__ float2 subi(float2 a, float2 b){ return make_float2(a.x + b.y, a.y - b.x); } // a - i*b

#define OUT_W(idx, val) do{ int _i = (idx); if ((unsigned)_i < (unsigned)osz) out[_i] = (val); }while(0)

// ---- twiddle table init (once per call; ~1us) ----
__global__ void k_twiddle(){
  int i = blockIdx.x*256 + threadIdx.x;
  if (i >= 512) return;
  if (i == 0){ g_tw[0] = make_float2(1.f, 0.f); return; }
  int h = 1 << (31 - __clz(i));
  int k = i - h;
  double a = -M_PI * (double)k / (double)h;
  g_tw[i] = make_float2((float)cos(a), (float)sin(a));
}

// ---- single-column radix-2 FFTs, separate re/im (row kernels) ----
template<int N, bool INV>
__device__ inline void fft_dif_sc(float* re, float* im, int tid, int nthr){
  for (int half = N >> 1; half >= 1; half >>= 1){
    __syncthreads();
    for (int b = tid; b < (N>>1); b += nthr){
      int k  = b & (half - 1);
      int i0 = ((b - k) << 1) + k;
      int i1 = i0 + half;
      float2 w = g_tw[half + k];
      float wy = INV ? -w.y : w.y;
      float ar = re[i0], ai = im[i0], br = re[i1], bi = im[i1];
      float dr = ar - br, di = ai - bi;
      re[i0] = ar + br; im[i0] = ai + bi;
      re[i1] = dr*w.x - di*wy;
      im[i1] = dr*wy + di*w.x;
    }
  }
  __syncthreads();
}

// ==== radix-4 multi-column machinery (8 cols/block, LDS float2 [row*9 + col]) ====

// fold: first radix-4 DIF stage (q=128) for 512-pt with input rows 256..511 == 0.
// src points at column element [0][v], row stride 512 float2.
__device__ __forceinline__ void fold512_load(const float2* src, float2* buf, int c, int rr){
  for (int i = rr; i < 128; i += 32){
    float2 a = src[(size_t)i*512];
    float2 b = src[(size_t)(i+128)*512];
    float2 w1 = g_tw[256+i], w2 = g_tw[128+i];
    float2 w3 = cmul(w1, w2);
    buf[i*9+c]       = cadd(a,b);
    buf[(i+128)*9+c] = cmul(subi(a,b), w1);
    buf[(i+256)*9+c] = cmul(csub(a,b), w2);
    buf[(i+384)*9+c] = cmul(addi(a,b), w3);
  }
}

// forward radix-4 stages q = 32, 8, 2 (after the folded q=128 stage)
__device__ __forceinline__ void dif4_stages_512(float2* buf, int c, int rr){
  #pragma unroll
  for (int q = 32; q >= 2; q >>= 2){
    __syncthreads();
    for (int g = rr; g < 128; g += 32){
      int k = g & (q-1);
      int base = ((g - k) << 2) + k;
      float2 x0 = buf[base*9+c], x1 = buf[(base+q)*9+c];
      float2 x2 = buf[(base+2*q)*9+c], x3 = buf[(base+3*q)*9+c];
      float2 t0=cadd(x0,x2), t1=csub(x0,x2), t2=cadd(x1,x3), t3=csub(x1,x3);
      float2 y0=cadd(t0,t2), y1=subi(t1,t3), y2=csub(t0,t2), y3=addi(t1,t3);
      float2 w1 = g_tw[2*q+k], w2 = g_tw[q+k];
      float2 w3 = cmul(w1,w2);
      buf[base*9+c]       = y0;
      buf[(base+q)*9+c]   = cmul(y1,w1);
      buf[(base+2*q)*9+c] = cmul(y2,w2);
      buf[(base+3*q)*9+c] = cmul(y3,w3);
    }
  }
}

// ---------------- g-MLP: one pass over 256x256 pixels (batch-independent) ----------------
__global__ __launch_bounds__(256) void k_gmlp(
    const float* gw0, const float* gb0, const float* gw1, const float* gb1,
    const float* l1w_g, const float* l1b_g, const float* gw2, const float* gb2,
    const float* l2w_g, const float* l2b_g, const float* gw3, const float* gb3,
    float* out, int osz, int offG, int offPhs, int interleaved)
{
  __shared__ float w0[60*32];
  __shared__ float w1[32*32];
  __shared__ float w2[32*32];
  __shared__ float b0[32], b1[32], b2[32], l1w[32], l1b[32], l2w[32], l2b[32], w3[32];
  __shared__ float b3s;
  int tid = threadIdx.x;
  for (int i = tid; i < 60*32; i += 256) w0[i] = gw0[i];
  for (int i = tid; i < 1024; i += 256){ w1[i] = gw1[i]; w2[i] = gw2[i]; }
  if (tid < 32){
    b0[tid]=gb0[tid]; b1[tid]=gb1[tid]; b2[tid]=gb2[tid];
    l1w[tid]=l1w_g[tid]; l1b[tid]=l1b_g[tid]; l2w[tid]=l2w_g[tid]; l2b[tid]=l2b_g[tid];
    w3[tid]=gw3[tid];
  }
  if (tid == 0) b3s = gb3[0];
  __syncthreads();

  int p = blockIdx.x * 256 + tid;
  int r = p >> 8, c = p & 255;
  float x = (float)(-1.0 + (2.0 * c) / 255.0);
  float y = (float)(-1.0 + (2.0 * r) / 255.0);

  float h0[32];
  #pragma unroll
  for (int j = 0; j < 32; j++) h0[j] = b0[j];
  for (int i = 1; i <= 15; i++){
    float sx, cx, sy, cy;
    sincosf((float)i * x, &sx, &cx);
    sincosf((float)i * y, &sy, &cy);
    const float* r0 = &w0[(4*(i-1)+0)*32];
    const float* r1 = &w0[(4*(i-1)+1)*32];
    const float* r2 = &w0[(4*(i-1)+2)*32];
    const float* r3 = &w0[(4*(i-1)+3)*32];
    #pragma unroll
    for (int j = 0; j < 32; j++)
      h0[j] += sx*r0[j] + sy*r1[j] + cx*r2[j] + cy*r3[j];
  }

  float h1[32];
  #pragma unroll
  for (int j = 0; j < 32; j++) h1[j] = b1[j];
  for (int k = 0; k < 32; k++){
    float v = h0[k];
    const float* row = &w1[k*32];
    #pragma unroll
    for (int j = 0; j < 32; j++) h1[j] += v * row[j];
  }
  {
    float m = 0.f;
    #pragma unroll
    for (int j = 0; j < 32; j++) m += h1[j];
    m *= (1.0f/32.0f);
    float vv = 0.f;
    #pragma unroll
    for (int j = 0; j < 32; j++){ float d = h1[j]-m; vv += d*d; }
    vv *= (1.0f/32.0f);
    float inv = rsqrtf(vv + 1e-5f);
    #pragma unroll
    for (int j = 0; j < 32; j++){
      float t = (h1[j]-m)*inv*l1w[j] + l1b[j];
      h1[j] = (t > 0.f) ? t : 0.01f*t;
    }
  }

  float h2[32];
  #pragma unroll
  for (int j = 0; j < 32; j++) h2[j] = b2[j];
  for (int k = 0; k < 32; k++){
    float v = h1[k];
    const float* row = &w2[k*32];
    #pragma unroll
    for (int j = 0; j < 32; j++) h2[j] += v * row[j];
  }
  {
    float m = 0.f;
    #pragma unroll
    for (int j = 0; j < 32; j++) m += h2[j];
    m *= (1.0f/32.0f);
    float vv = 0.f;
    #pragma unroll
    for (int j = 0; j < 32; j++){ float d = h2[j]-m; vv += d*d; }
    vv *= (1.0f/32.0f);
    float inv = rsqrtf(vv + 1e-5f);
    #pragma unroll
    for (int j = 0; j < 32; j++){
      float t = (h2[j]-m)*inv*l2w[j] + l2b[j];
      h2[j] = (t > 0.f) ? t : 0.01f*t;
    }
  }

  float phs = b3s;
  #pragma unroll
  for (int k = 0; k < 32; k++) phs += h2[k]*w3[k];

  float sp, cp; sincosf(phs, &sp, &cp);
  g_cs[p] = make_float2(cp, sp);

  #pragma unroll
  for (int b = 0; b < 16; b++){
    OUT_W(offPhs + b*65536 + p, phs);
    if (interleaved){
      OUT_W(offG + 2*(b*65536 + p),     cp);
      OUT_W(offG + 2*(b*65536 + p) + 1, sp);
    } else {
      OUT_W(offG + b*65536 + p, cp);
    }
  }
}

// ---------------- patch MLPs -> I_est ----------------
__global__ __launch_bounds__(256) void k_patch(
    const float* pdata, const float* rw0, const float* rb0,
    const float* rw1, const float* rb1, const float* rw2, const float* rb2,
    float* out, int osz, int offIest)
{
  __shared__ float w0[1024];
  __shared__ float w1[1024];
  __shared__ float b0[32], b1[32], w2[32];
  __shared__ float b2s;
  int patch = blockIdx.x >> 6;
  int tid = threadIdx.x;
  for (int i = tid; i < 1024; i += 256){ w0[i] = rw0[patch*1024 + i]; w1[i] = rw1[patch*1024 + i]; }
  if (tid < 32){ b0[tid]=rb0[patch*32+tid]; b1[tid]=rb1[patch*32+tid]; w2[tid]=rw2[patch*32+tid]; }
  if (tid == 0) b2s = rb2[patch];
  __syncthreads();

  int p = (blockIdx.x & 63) * 256 + tid;
  int i = p >> 7, j = p & 127;
  int i1 = min(i+1, 127), j1 = min(j+1, 127);
  const float* base = pdata + (size_t)patch * 128*128*32;
  const float* d00 = base + (i*128 + j )*32;
  const float* d01 = base + (i*128 + j1)*32;
  const float* d10 = base + (i1*128 + j )*32;
  const float* d11 = base + (i1*128 + j1)*32;

  float f[32];
  #pragma unroll
  for (int k = 0; k < 32; k++) f[k] = 0.25f*(d00[k]+d01[k]+d10[k]+d11[k]);

  float h[32];
  #pragma unroll
  for (int q = 0; q < 32; q++) h[q] = b0[q];
  for (int k = 0; k < 32; k++){
    float v = f[k];
    const float* row = &w0[k*32];
    #pragma unroll
    for (int q = 0; q < 32; q++) h[q] += v*row[q];
  }
  #pragma unroll
  for (int q = 0; q < 32; q++) h[q] = fmaxf(h[q], 0.f);

  float g[32];
  #pragma unroll
  for (int q = 0; q < 32; q++) g[q] = b1[q];
  for (int k = 0; k < 32; k++){
    float v = h[k];
    const float* row = &w1[k*32];
    #pragma unroll
    for (int q = 0; q < 32; q++) g[q] += v*row[q];
  }
  float o = b2s;
  #pragma unroll
  for (int k = 0; k < 32; k++) o += fmaxf(g[k], 0.f)*w2[k];

  int pr = (patch >> 1)*128 + i;
  int pc = (patch & 1)*128 + j;
  g_I[pr*256 + pc] = o;
  OUT_W(offIest + pr*256 + pc, o);
}

// ---------------- norm = 65536*sum(x^2), two-stage ----------------
__global__ __launch_bounds__(256) void k_norm1(const float* x){
  int tid = threadIdx.x;
  float4 v = ((const float4*)x)[(size_t)blockIdx.x*256 + tid];
  float s = v.x*v.x + v.y*v.y + v.z*v.z + v.w*v.w;
  __shared__ float red[256];
  red[tid] = s; __syncthreads();
  for (int w = 128; w > 0; w >>= 1){ if (tid < w) red[tid] += red[tid+w]; __syncthreads(); }
  if (tid == 0) g_partial[blockIdx.x] = red[0];
}

__global__ __launch_bounds__(256) void k_norm2(){
  int tid = threadIdx.x;
  int b = tid >> 4, l = tid & 15;
  float s = 0.f;
  #pragma unroll
  for (int j = 0; j < 4; j++) s += g_partial[b*64 + l + 16*j];
  #pragma unroll
  for (int d = 8; d > 0; d >>= 1) s += __shfl_down(s, d, 16);
  if (l == 0) g_norms[b] = 65536.0f * s;
}

// ---------------- field FFT (256): rows ----------------
__global__ __launch_bounds__(128) void k_fft_field_row(const float* x){
  int b = blockIdx.x >> 8, r = blockIdx.x & 255;
  __shared__ float re[256], im[256];
  int tid = threadIdx.x;
  for (int e = tid; e < 256; e += 128){
    float xv = x[((size_t)b*256 + r)*256 + e];
    float2 cs = g_cs[r*256 + e];
    re[e] = xv*cs.x; im[e] = xv*cs.y;
  }
  fft_dif_sc<256,false>(re, im, tid, 128);
  for (int e = tid; e < 256; e += 128)
    g_F[((size_t)b*256 + r)*256 + rev8(e)] = make_float2(re[e], im[e]);
}

// ---------------- field FFT: cols, radix-4, 8 per block, in place ----------------
__global__ __launch_bounds__(256) void k_fft_field_col(){
  __shared__ float2 buf[256*9];
  int b = blockIdx.x >> 5, v0 = (blockIdx.x & 31) << 3;
  int tid = threadIdx.x, c = tid & 7, rr = tid >> 3;
  const float2* Fr = &g_F[(size_t)b*256*256 + v0 + c];
  for (int r = rr; r < 256; r += 32) buf[r*9+c] = Fr[(size_t)r*256];
  #pragma unroll
  for (int q = 64; q >= 1; q >>= 2){
    __syncthreads();
    for (int g = rr; g < 64; g += 32){
      int k = g & (q-1);
      int base = ((g - k) << 2) + k;
      float2 x0 = buf[base*9+c], x1 = buf[(base+q)*9+c];
      float2 x2 = buf[(base+2*q)*9+c], x3 = buf[(base+3*q)*9+c];
      float2 t0=cadd(x0,x2), t1=csub(x0,x2), t2=cadd(x1,x3), t3=csub(x1,x3);
      float2 y0=cadd(t0,t2), y1=subi(t1,t3), y2=csub(t0,t2), y3=addi(t1,t3);
      if (q > 1){
        float2 w1 = g_tw[2*q+k], w2 = g_tw[q+k];
        float2 w3 = cmul(w1,w2);
        y1 = cmul(y1,w1); y2 = cmul(y2,w2); y3 = cmul(y3,w3);
      }
      buf[base*9+c]=y0; buf[(base+q)*9+c]=y1; buf[(base+2*q)*9+c]=y2; buf[(base+3*q)*9+c]=y3;
    }
  }
  __syncthreads();
  float2* Fw = &g_F[(size_t)b*256*256 + v0 + c];
  for (int p = rr; p < 256; p += 32)
    Fw[(size_t)rev4d8(p)*256] = buf[p*9+c];   // digit-reversed store -> natural bin order
}

// ------- fused: kernel magnitude (shift+flip+normalize) -> d_out, then padded row FFT -> KA -------
__global__ __launch_bounds__(256) void k_mag_krow(float* out, int osz, int offKer){
  int b = blockIdx.x >> 8, r = blockIdx.x & 255;
  __shared__ float re[512], im[512];
  int tid = threadIdx.x;
  float invn = 1.0f / g_norms[b];
  int a = (127 - r) & 255;
  for (int e = tid; e < 512; e += 256){
    float kv = 0.f;
    if (e < 256){
      int bb = (127 - e) & 255;
      float2 f = g_F[((size_t)b*256 + a)*256 + bb];
      kv = (f.x*f.x + f.y*f.y) * invn;
      OUT_W(offKer + b*65536 + r*256 + e, kv);
    }
    re[e] = kv; im[e] = 0.f;
  }
  fft_dif_sc<512,false>(re, im, tid, 256);
  for (int e = tid; e < 512; e += 256)
    g_KA[((size_t)b*256 + r)*512 + rev9(e)] = make_float2(re[e], im[e]);
}

// ---------------- Sf row pass = FFT(pad512(I_est rows)) ----------------
__global__ __launch_bounds__(256) void k_fft_S_row(){
  int r = blockIdx.x;
  __shared__ float re[512], im[512];
  int tid = threadIdx.x;
  for (int e = tid; e < 512; e += 256){
    re[e] = (e < 256) ? g_I[r*256 + e] : 0.f;
    im[e] = 0.f;
  }
  fft_dif_sc<512,false>(re, im, tid, 256);
  for (int e = tid; e < 512; e += 256) g_SfA[r*512 + rev9(e)] = make_float2(re[e], im[e]);
}

// ---- Sf col pass: SAME forward pipeline as col_mul_inv -> g_Sf stored in pi order ----
__global__ __launch_bounds__(256) void k_fft_S_col(){
  __shared__ float2 buf[512*9];
  int v0 = blockIdx.x << 3;
  int tid = threadIdx.x, c = tid & 7, rr = tid >> 3;
  int v = v0 + c;
  fold512_load(&g_SfA[v], buf, c, rr);
  dif4_stages_512(buf, c, rr);
  __syncthreads();
  // final radix-2 stage (q=1), store directly from registers (linear pi order)
  for (int g = rr; g < 256; g += 32){
    int i0 = 2*g;
    float2 a = buf[i0*9+c], b = buf[(i0+1)*9+c];
    g_Sf[(size_t)i0*512 + v]     = cadd(a,b);
    g_Sf[(size_t)(i0+1)*512 + v] = csub(a,b);
  }
}

// ------- fused col pass: Kf col FFT (fold+r4) -> r2+mul+r2 -> inverse r4 -> partial last stage -------
__global__ __launch_bounds__(256) void k_col_mul_inv(){
  __shared__ float2 buf[512*9];
  int bi = blockIdx.x >> 6, v0 = (blockIdx.x & 63) << 3;
  int tid = threadIdx.x, c = tid & 7, rr = tid >> 3;
  int v = v0 + c;

  fold512_load(&g_KA[((size_t)bi*256)*512 + v], buf, c, rr);
  dif4_stages_512(buf, c, rr);

  // fused: forward r2 -> multiply by Sf (pi-aligned) -> inverse r2
  __syncthreads();
  for (int g = rr; g < 256; g += 32){
    int i0 = 2*g;
    float2 a = buf[i0*9+c], b = buf[(i0+1)*9+c];
    float2 y0 = cadd(a,b), y1 = csub(a,b);
    float2 s0 = g_Sf[(size_t)i0*512 + v];
    float2 s1 = g_Sf[(size_t)(i0+1)*512 + v];
    float2 z0 = cmul(y0,s0), z1 = cmul(y1,s1);
    buf[i0*9+c]     = cadd(z0,z1);
    buf[(i0+1)*9+c] = csub(z0,z1);
  }

  // inverse radix-4 stages q = 2, 8, 32
  #pragma unroll
  for (int q = 2; q <= 32; q <<= 2){
    __syncthreads();
    for (int g = rr; g < 128; g += 32){
      int k = g & (q-1);
      int base = ((g - k) << 2) + k;
      float2 z0 = buf[base*9+c], z1 = buf[(base+q)*9+c];
      float2 z2 = buf[(base+2*q)*9+c], z3 = buf[(base+3*q)*9+c];
      float2 w1 = g_tw[2*q+k], w2 = g_tw[q+k];
      float2 w3 = cmul(w1,w2);
      z1 = cmulj(z1,w1); z2 = cmulj(z2,w2); z3 = cmulj(z3,w3);
      float2 u0=cadd(z0,z2), u1=csub(z0,z2), u2=cadd(z1,z3), u3=csub(z1,z3);
      buf[base*9+c]       = cadd(u0,u2);
      buf[(base+q)*9+c]   = addi(u1,u3);
      buf[(base+2*q)*9+c] = csub(u0,u2);
      buf[(base+3*q)*9+c] = subi(u1,u3);
    }
  }

  // final inverse stage q=128: only rows 128..383 needed -> write P directly
  __syncthreads();
  for (int i = rr; i < 128; i += 32){
    float2 z0 = buf[i*9+c], z1 = buf[(i+128)*9+c];
    float2 z2 = buf[(i+256)*9+c], z3 = buf[(i+384)*9+c];
    float2 w1 = g_tw[256+i], w2 = g_tw[128+i];
    float2 w3 = cmul(w1,w2);
    z1 = cmulj(z1,w1); z2 = cmulj(z2,w2); z3 = cmulj(z3,w3);
    float2 u0=cadd(z0,z2), u1=csub(z0,z2), u2=cadd(z1,z3), u3=csub(z1,z3);
    g_P[((size_t)bi*256 + i)*512 + v]       = addi(u1,u3); // conv row i+128
    g_P[((size_t)bi*256 + i + 128)*512 + v] = csub(u0,u2); // conv row i+256
  }
}

// ---------------- inverse row FFT + crop + scale + real ----------------
__global__ __launch_bounds__(256) void k_ifft_row(float* out, int osz){
  int b = blockIdx.x >> 8, ri = blockIdx.x & 255;
  __shared__ float re[512], im[512];
  int tid = threadIdx.x;
  for (int e = tid; e < 512; e += 256){
    float2 p = g_P[((size_t)b*256 + ri)*512 + e];
    re[e] = p.x; im[e] = p.y;
  }
  fft_dif_sc<512,true>(re, im, tid, 256);      // inverse, natural in -> bit-rev out
  const float sc = 1.0f / 262144.0f;           // 1/(512*512)
  for (int e = tid; e < 512; e += 256){
    int vo = rev9(e);
    if (vo >= 128 && vo < 384)
      OUT_W(b*65536 + ri*256 + (vo - 128), re[e] * sc);
  }
}

extern "C" void kernel_launch(void* const* d_in, const int* in_sizes, int n_in,
                              void* d_out, int out_size, void* d_ws, size_t ws_size,
                              hipStream_t stream) {
  // ---- verify input ordering/sizes; if unexpected, launch nothing (clean diagnostic fail) ----
  static const int expect[21] = {
    16*65536, 16, 4*128*128*32,
    4*32*32, 4*32, 4*32*32, 4*32, 4*32, 4,
    60*32, 32, 32*32, 32, 32, 32, 32*32, 32, 32, 32, 32, 1
  };
  if (n_in < 21) return;
  for (int i = 0; i < 21; i++) if (in_sizes[i] != expect[i]) return;

  const float* x_batch = (const float*)d_in[0];
  const float* pdata = (const float*)d_in[2];
  const float* rw0 = (const float*)d_in[3];
  const float* rb0 = (const float*)d_in[4];
  const float* rw1 = (const float*)d_in[5];
  const float* rb1 = (const float*)d_in[6];
  const float* rw2 = (const float*)d_in[7];
  const float* rb2 = (const float*)d_in[8];
  const float* gw0 = (const float*)d_in[9];
  const float* gb0 = (const float*)d_in[10];
  const float* gw1 = (const float*)d_in[11];
  const float* gb1 = (const float*)d_in[12];
  const float* l1w = (const float*)d_in[13];
  const float* l1b = (const float*)d_in[14];
  const float* gw2 = (const float*)d_in[15];
  const float* gb2 = (const float*)d_in[16];
  const float* l2w = (const float*)d_in[17];
  const float* l2b = (const float*)d_in[18];
  const float* gw3 = (const float*)d_in[19];
  const float* gb3 = (const float*)d_in[20];

  float* out = (float*)d_out;

  // ---- output layout, adaptive on out_size ----
  int interleaved = (out_size >= 5308416) ? 1 : 0;
  int offKer  = 1048576;
  int offG    = 2097152;
  int offPhs  = interleaved ? 4194304 : 3145728;
  int offIest = interleaved ? 5242880 : 4194304;

  k_twiddle<<<2, 256, 0, stream>>>();
  k_gmlp<<<256, 256, 0, stream>>>(gw0, gb0, gw1, gb1, l1w, l1b, gw2, gb2,
                                  l2w, l2b, gw3, gb3, out, out_size, offG, offPhs, interleaved);
  k_patch<<<256, 256, 0, stream>>>(pdata, rw0, rb0, rw1, rb1, rw2, rb2, out, out_size, offIest);
  k_norm1<<<1024, 256, 0, stream>>>(x_batch);
  k_norm2<<<1, 256, 0, stream>>>();
  k_fft_S_row<<<256, 256, 0, stream>>>();
  k_fft_S_col<<<64, 256, 0, stream>>>();
  k_fft_field_row<<<4096, 128, 0, stream>>>(x_batch);
  k_fft_field_col<<<512, 256, 0, stream>>>();
  k_mag_krow<<<4096, 256, 0, stream>>>(out, out_size, offKer);
  k_col_mul_inv<<<1024, 256, 0, stream>>>();
  k_ifft_row<<<4096, 256, 0, stream>>>(out, out_size);
}